// Round 2
// baseline (348.454 us; speedup 1.0000x reference)
//
#include <hip/hip_runtime.h>
#include <hip/hip_bf16.h>
#include <stdint.h>

#define HIDDEN 1024
#define TOKENS 32768
#define NE 8

typedef unsigned short u16;
typedef short bf16x8 __attribute__((ext_vector_type(8)));
typedef float f32x4 __attribute__((ext_vector_type(4)));

__device__ __forceinline__ void gload_lds16(const void* g, void* l) {
  __builtin_amdgcn_global_load_lds(
      (const __attribute__((address_space(1))) void*)g,
      (__attribute__((address_space(3))) void*)l, 16, 0, 0);
}

// ---------------- K0: expert_weight [h][d] fp32 -> Bt [d][h] bf16 (transpose+convert)
__global__ __launch_bounds__(256) void k0_transpose(const float* __restrict__ B,
                                                    u16* __restrict__ Bt) {
  __shared__ float tile[64][65];
  const int d0 = blockIdx.x * 64;
  const int h0 = blockIdx.y * 64;
  const int t = threadIdx.x;
#pragma unroll
  for (int p = 0; p < 16; ++p) {
    int idx = p * 256 + t;
    int r = idx >> 6, c = idx & 63;
    tile[r][c] = B[(size_t)(h0 + r) * HIDDEN + d0 + c];
  }
  __syncthreads();
#pragma unroll
  for (int p = 0; p < 16; ++p) {
    int idx = p * 256 + t;
    int r = idx >> 6, c = idx & 63;
    __hip_bfloat16 v = __float2bfloat16(tile[c][r]);
    Bt[(size_t)(d0 + r) * HIDDEN + h0 + c] = *(u16*)&v;
  }
}

// ---------------- K1: fp32 gating -> s[tok]; emit A bf16. Gate weights in LDS.
// 1024 blocks x 512 threads: 8192 waves, 4 contiguous tokens/wave (2 pairs).
__global__ __launch_bounds__(512) void k1_gate(const float* __restrict__ H,
                                               const float* __restrict__ G,
                                               float* __restrict__ s,
                                               u16* __restrict__ Abf) {
  __shared__ float Gs[NE * HIDDEN];  // 32 KiB
  const int t = threadIdx.x;
#pragma unroll
  for (int i = 0; i < 4; ++i)
    ((float4*)Gs)[i * 512 + t] = ((const float4*)G)[i * 512 + t];
  __syncthreads();

  const int lane = t & 63;
  const int wave = t >> 6;
  const int gw = blockIdx.x * 8 + wave;
  const int tok0 = gw * 4;

#pragma unroll
  for (int tp = 0; tp < 2; ++tp) {
    const int tok = tok0 + tp * 2;
    const float* h0p = H + (size_t)tok * HIDDEN;
    const float* h1p = h0p + HIDDEN;
    float4 h0[4], h1[4];
#pragma unroll
    for (int p = 0; p < 4; ++p) {
      h0[p] = *(const float4*)(h0p + p * 256 + lane * 4);
      h1[p] = *(const float4*)(h1p + p * 256 + lane * 4);
    }
    // fused bf16 A writes (8B/lane, coalesced)
#pragma unroll
    for (int p = 0; p < 4; ++p) {
      __hip_bfloat162 lo0 = __float22bfloat162_rn(make_float2(h0[p].x, h0[p].y));
      __hip_bfloat162 hi0 = __float22bfloat162_rn(make_float2(h0[p].z, h0[p].w));
      uint2 pk0;
      pk0.x = *(unsigned*)&lo0;
      pk0.y = *(unsigned*)&hi0;
      *(uint2*)(Abf + (size_t)tok * HIDDEN + p * 256 + lane * 4) = pk0;
      __hip_bfloat162 lo1 = __float22bfloat162_rn(make_float2(h1[p].x, h1[p].y));
      __hip_bfloat162 hi1 = __float22bfloat162_rn(make_float2(h1[p].z, h1[p].w));
      uint2 pk1;
      pk1.x = *(unsigned*)&lo1;
      pk1.y = *(unsigned*)&hi1;
      *(uint2*)(Abf + (size_t)(tok + 1) * HIDDEN + p * 256 + lane * 4) = pk1;
    }

    float a0[NE], a1[NE];
#pragma unroll
    for (int e = 0; e < NE; ++e) { a0[e] = 0.f; a1[e] = 0.f; }
#pragma unroll
    for (int p = 0; p < 4; ++p)
#pragma unroll
      for (int e = 0; e < NE; ++e) {
        float4 w = *(const float4*)&Gs[e * HIDDEN + p * 256 + lane * 4];
        a0[e] += h0[p].x * w.x + h0[p].y * w.y + h0[p].z * w.z + h0[p].w * w.w;
        a1[e] += h1[p].x * w.x + h1[p].y * w.y + h1[p].z * w.z + h1[p].w * w.w;
      }
    // stage 1: butterfly over lanes 1,2,4 -> 8-lane-group sums for all experts
#pragma unroll
    for (int st = 1; st <= 4; st <<= 1)
#pragma unroll
      for (int e = 0; e < NE; ++e) {
        a0[e] += __shfl_xor(a0[e], st, 64);
        a1[e] += __shfl_xor(a1[e], st, 64);
      }
    // stage 2: each lane selects its own expert (eid = lane&7), static cndmask tree
    const bool b0 = lane & 1, b1 = lane & 2, b2 = lane & 4;
    float t01 = b0 ? a0[1] : a0[0], t23 = b0 ? a0[3] : a0[2];
    float t45 = b0 ? a0[5] : a0[4], t67 = b0 ? a0[7] : a0[6];
    float u03 = b1 ? t23 : t01, u47 = b1 ? t67 : t45;
    float v0 = b2 ? u47 : u03;
    float s01 = b0 ? a1[1] : a1[0], s23 = b0 ? a1[3] : a1[2];
    float s45 = b0 ? a1[5] : a1[4], s67 = b0 ? a1[7] : a1[6];
    float w03 = b1 ? s23 : s01, w47 = b1 ? s67 : s45;
    float v1 = b2 ? w47 : w03;
    // stage 3: sum across the 8 groups
    v0 += __shfl_xor(v0, 8, 64);
    v0 += __shfl_xor(v0, 16, 64);
    v0 += __shfl_xor(v0, 32, 64);
    v1 += __shfl_xor(v1, 8, 64);
    v1 += __shfl_xor(v1, 16, 64);
    v1 += __shfl_xor(v1, 32, 64);
    // top-2 merge across the 8 experts held by lanes 0..7 of each group
    float m1a = v0, m2a = -3.0e38f, m1b = v1, m2b = -3.0e38f;
#pragma unroll
    for (int st = 1; st <= 4; st <<= 1) {
      float o1 = __shfl_xor(m1a, st, 64);
      float o2 = __shfl_xor(m2a, st, 64);
      float lo = fminf(m1a, o1);
      m1a = fmaxf(m1a, o1);
      m2a = fmaxf(lo, fmaxf(m2a, o2));
      float p1 = __shfl_xor(m1b, st, 64);
      float p2 = __shfl_xor(m2b, st, 64);
      float lo2 = fminf(m1b, p1);
      m1b = fmaxf(m1b, p1);
      m2b = fmaxf(lo2, fmaxf(m2b, p2));
    }
    if (lane == 0) {
      s[tok] = m1a + m2a;
      s[tok + 1] = m1b + m2b;
    }
  }
}

// ---------------- K2: C[m][n] = sum_k A[m][k]*Bt[n][k], bf16 MFMA
// 256x256 tile, BK=32, 8 waves (2M x 4N), double-buffered LDS (64 KiB),
// counted vmcnt pipeline (T3/T4): loads for tile t+2 in flight under tile t's MFMAs.
#define BM2 256
#define BN2 256
#define BK2 32

__global__ __launch_bounds__(512, 2) void k2_gemm(const u16* __restrict__ A,
                                                  const u16* __restrict__ Bt,
                                                  u16* __restrict__ C) {
  __shared__ u16 smem[2 * 2 * 8192];  // [buf][mat][256 rows * 4 chunks * 8] = 64 KiB
  const int t = threadIdx.x;
  const int lane = t & 63;
  const int wave = t >> 6;

  // XCD-aware: xcd = b&7 owns 16 consecutive m-panels; 4 n-tiles of each
  // m-panel consecutive within the XCD (A-panel L2 reuse; all of B L2-resident).
  const int b = blockIdx.x;
  const int tile = (b & 7) * 64 + (b >> 3);
  const int m0 = (tile >> 2) * BM2;
  const int n0 = (tile & 3) * BN2;

  const int wmb = (wave >> 2) * 128;  // wave rows base (2 M-waves)
  const int wnb = (wave & 3) * 64;    // wave cols base (4 N-waves)
  const int lm = lane & 15;
  const int lq = lane >> 4;

  // staging: 1024 chunk-slots per matrix, 512 threads -> 2 slots each.
  // LDS slot (r,qs) holds global k-chunk q = qs ^ sw(r), sw(r)=(r^(r>>2))&3.
  const int r0 = t >> 2, r1 = (512 + t) >> 2;
  const int q0 = (t & 3) ^ ((r0 ^ (r0 >> 2)) & 3);
  const int q1 = (t & 3) ^ ((r1 ^ (r1 >> 2)) & 3);
  const u16* gA0 = A + (size_t)(m0 + r0) * HIDDEN + q0 * 8;
  const u16* gA1 = A + (size_t)(m0 + r1) * HIDDEN + q1 * 8;
  const u16* gB0 = Bt + (size_t)(n0 + r0) * HIDDEN + q0 * 8;
  const u16* gB1 = Bt + (size_t)(n0 + r1) * HIDDEN + q1 * 8;
  const int lds0 = t * 8;          // elem offset inside a matrix region
  const int lds1 = (512 + t) * 8;  // (wave-uniform base + lane*16B: gload_lds-legal)

  f32x4 acc[8][4];
#pragma unroll
  for (int i = 0; i < 8; ++i)
#pragma unroll
    for (int j = 0; j < 4; ++j) acc[i][j] = (f32x4){0.f, 0.f, 0.f, 0.f};

#define STAGE(buf, kk)                                   \
  do {                                                   \
    u16* base_ = smem + (buf) * 16384;                   \
    gload_lds16(gA0 + (kk), base_ + lds0);               \
    gload_lds16(gA1 + (kk), base_ + lds1);               \
    gload_lds16(gB0 + (kk), base_ + 8192 + lds0);        \
    gload_lds16(gB1 + (kk), base_ + 8192 + lds1);        \
  } while (0)

  // prologue: tiles 0 and 1 in flight; wait tile 0 only (vmcnt counts in order)
  STAGE(0, 0);
  STAGE(1, BK2);
  asm volatile("s_waitcnt vmcnt(4)" ::: "memory");
  asm volatile("s_barrier" ::: "memory");

  int cur = 0;
  for (int tt = 0; tt < 32; ++tt) {
    const u16* As = smem + cur * 16384;
    const u16* Bs = As + 8192;
    bf16x8 af[8], bfr[4];
#pragma unroll
    for (int i = 0; i < 8; ++i) {
      int r = wmb + i * 16 + lm;
      int qs = lq ^ ((r ^ (r >> 2)) & 3);
      af[i] = *(const bf16x8*)&As[(r * 4 + qs) * 8];
    }
#pragma unroll
    for (int j = 0; j < 4; ++j) {
      int r = wnb + j * 16 + lm;
      int qs = lq ^ ((r ^ (r >> 2)) & 3);
      bfr[j] = *(const bf16x8*)&Bs[(r * 4 + qs) * 8];
    }
    __builtin_amdgcn_s_setprio(1);
#pragma unroll
    for (int i = 0; i < 8; ++i)
#pragma unroll
      for (int j = 0; j < 4; ++j)
        acc[i][j] = __builtin_amdgcn_mfma_f32_16x16x32_bf16(af[i], bfr[j], acc[i][j], 0, 0, 0);
    __builtin_amdgcn_s_setprio(0);
    // all of this wave's ds_reads of buf[cur] complete before anyone overwrites it
    asm volatile("s_waitcnt lgkmcnt(0)" ::: "memory");
    asm volatile("s_barrier" ::: "memory");
    if (tt + 2 < 32) {
      STAGE(cur, (tt + 2) * BK2);
      // wait tile t+1's 4 loads (oldest); t+2's 4 stay in flight across barrier
      asm volatile("s_waitcnt vmcnt(4)" ::: "memory");
    } else {
      asm volatile("s_waitcnt vmcnt(0)" ::: "memory");
    }
    asm volatile("s_barrier" ::: "memory");
    cur ^= 1;
  }
#undef STAGE

  // epilogue: C/D layout col=lane&15, row=(lane>>4)*4+reg
#pragma unroll
  for (int i = 0; i < 8; ++i) {
#pragma unroll
    for (int rr = 0; rr < 4; ++rr) {
      int row = m0 + wmb + i * 16 + lq * 4 + rr;
      size_t base = (size_t)row * HIDDEN + n0 + wnb + lm;
#pragma unroll
      for (int j = 0; j < 4; ++j) {
        __hip_bfloat16 v = __float2bfloat16(acc[i][j][rr]);
        C[base + j * 16] = *(u16*)&v;
      }
    }
  }
}

// ---------------- K3: LayerNorm( s[tok] * C[tok][:] ) -> out fp32 (nontemporal stores)
__global__ __launch_bounds__(256) void k3_ln(const u16* __restrict__ C,
                                             const float* __restrict__ s,
                                             const float* __restrict__ gamma,
                                             const float* __restrict__ beta,
                                             float* __restrict__ out) {
  const int t = threadIdx.x;
  const int lane = t & 63;
  const int tok = blockIdx.x * 4 + (t >> 6);
  const float sc = s[tok];
  const uint4* row = (const uint4*)(C + (size_t)tok * HIDDEN);
  float x[16];
  float sum = 0.f, sq = 0.f;
#pragma unroll
  for (int p = 0; p < 2; ++p) {
    union { uint4 u; u16 us[8]; } v;
    v.u = row[p * 64 + lane];
#pragma unroll
    for (int i = 0; i < 8; ++i) {
      float f = __uint_as_float(((unsigned)v.us[i]) << 16) * sc;
      x[p * 8 + i] = f;
      sum += f;
      sq += f * f;
    }
  }
#pragma unroll
  for (int off = 32; off > 0; off >>= 1) {
    sum += __shfl_xor(sum, off, 64);
    sq += __shfl_xor(sq, off, 64);
  }
  const float mean = sum * (1.f / HIDDEN);
  const float var = sq * (1.f / HIDDEN) - mean * mean;
  const float rstd = rsqrtf(var + 1e-5f);
  const float4* g4 = (const float4*)gamma;
  const float4* b4 = (const float4*)beta;
#pragma unroll
  for (int p = 0; p < 2; ++p) {
    int e4 = (p * 64 + lane) * 2;
    float4 gm0 = g4[e4], gm1 = g4[e4 + 1];
    float4 bt0 = b4[e4], bt1 = b4[e4 + 1];
    f32x4 o0, o1;
    o0[0] = (x[p * 8 + 0] - mean) * rstd * gm0.x + bt0.x;
    o0[1] = (x[p * 8 + 1] - mean) * rstd * gm0.y + bt0.y;
    o0[2] = (x[p * 8 + 2] - mean) * rstd * gm0.z + bt0.z;
    o0[3] = (x[p * 8 + 3] - mean) * rstd * gm0.w + bt0.w;
    o1[0] = (x[p * 8 + 4] - mean) * rstd * gm1.x + bt1.x;
    o1[1] = (x[p * 8 + 5] - mean) * rstd * gm1.y + bt1.y;
    o1[2] = (x[p * 8 + 6] - mean) * rstd * gm1.z + bt1.z;
    o1[3] = (x[p * 8 + 7] - mean) * rstd * gm1.w + bt1.w;
    float* op = out + (size_t)tok * HIDDEN + e4 * 4;
    __builtin_nontemporal_store(o0, (f32x4*)op);
    __builtin_nontemporal_store(o1, (f32x4*)(op + 4));
  }
}

extern "C" void kernel_launch(void* const* d_in, const int* in_sizes, int n_in,
                              void* d_out, int out_size, void* d_ws, size_t ws_size,
                              hipStream_t stream) {
  (void)in_sizes; (void)n_in; (void)out_size; (void)ws_size;
  const float* H = (const float*)d_in[0];      // [4,8192,1024] fp32
  const float* G = (const float*)d_in[1];      // [8,1024] fp32
  const float* W = (const float*)d_in[2];      // [1024,1024] fp32
  const float* gamma = (const float*)d_in[3];  // [1024]
  const float* beta = (const float*)d_in[4];   // [1024]
  float* out = (float*)d_out;

  char* ws = (char*)d_ws;
  u16* Bt = (u16*)ws;                                        // 2 MiB
  float* s = (float*)(ws + (size_t)(2u << 20));              // 128 KiB
  u16* C = (u16*)(ws + (size_t)(2u << 20) + (256u << 10));   // 64 MiB

  // A-bf16 scratch lives in d_out's first 67 MB; k2 consumes it, k3 overwrites.
  u16* Abf = (u16*)d_out;

  k0_transpose<<<dim3(16, 16), 256, 0, stream>>>(W, Bt);
  k1_gate<<<1024, 512, 0, stream>>>(H, G, s, Abf);
  k2_gemm<<<512, 512, 0, stream>>>(Abf, Bt, C);
  k3_ln<<<TOKENS / 4, 256, 0, stream>>>(C, s, gamma, beta, out);
}